// Round 1
// baseline (203.715 us; speedup 1.0000x reference)
//
#include <hip/hip_runtime.h>

// GRU (B=4096, T=512, I=1, H=32) + FC(32->12), fully fused, f32.
//
// Layout: lane = (batch, hidden unit j). 32 lanes per batch element,
// 2 batch elements per wave64, 8 per 256-thread block. 2048 waves total
// = 2 waves/SIMD over the whole chip. Each lane holds the three w_hh rows
// (r,z,n gates for its unit) in 96 VGPRs; the h vector is exchanged through
// one 32-float LDS row per group. All lanes of a group are in the same wave,
// so no __syncthreads is ever needed (wave-lockstep + lgkmcnt ordering).

namespace {

constexpr int kH = 32;
constexpr int kT = 512;
constexpr int kO = 12;
constexpr int kGroups = 8;  // 256 threads / 32 lanes

__device__ __forceinline__ float fast_sigmoid(float a) {
    // 1 / (1 + e^-a); v_exp + v_rcp, ~1 ulp each, fine vs 5.6e-3 tolerance
    float e = __expf(-a);
    return __builtin_amdgcn_rcpf(1.0f + e);
}

__device__ __forceinline__ float fast_tanh(float a) {
    // tanh(a) = 1 - 2/(e^{2a}+1); saturates correctly at +-inf
    float e = __expf(2.0f * a);
    return fmaf(-2.0f, __builtin_amdgcn_rcpf(e + 1.0f), 1.0f);
}

__global__ __launch_bounds__(256, 2) void gru_fused(
    const float* __restrict__ x,      // [4096, 512, 1]
    const float* __restrict__ w_ih,   // [96, 1]
    const float* __restrict__ w_hh,   // [96, 32]
    const float* __restrict__ b_ih,   // [96]
    const float* __restrict__ b_hh,   // [96]
    const float* __restrict__ fc_w,   // [12, 32]
    const float* __restrict__ fc_b,   // [12]
    float* __restrict__ out)          // [4096, 12]
{
    __shared__ float hbuf[kGroups][kH];

    const int tid = threadIdx.x;
    const int g   = tid >> 5;         // group (batch slot) within block
    const int j   = tid & 31;         // hidden unit owned by this lane
    const int b   = blockIdx.x * kGroups + g;

    // ---- per-lane weights: w_hh rows j (r), j+32 (z), j+64 (n) ----
    float wr[kH], wz[kH], wn[kH];
    {
        const float4* Wr = reinterpret_cast<const float4*>(w_hh + j * kH);
        const float4* Wz = reinterpret_cast<const float4*>(w_hh + (j + kH) * kH);
        const float4* Wn = reinterpret_cast<const float4*>(w_hh + (j + 2 * kH) * kH);
#pragma unroll
        for (int q = 0; q < kH / 4; ++q) {
            float4 a = Wr[q];
            wr[4 * q + 0] = a.x; wr[4 * q + 1] = a.y;
            wr[4 * q + 2] = a.z; wr[4 * q + 3] = a.w;
            float4 c = Wz[q];
            wz[4 * q + 0] = c.x; wz[4 * q + 1] = c.y;
            wz[4 * q + 2] = c.z; wz[4 * q + 3] = c.w;
            float4 d = Wn[q];
            wn[4 * q + 0] = d.x; wn[4 * q + 1] = d.y;
            wn[4 * q + 2] = d.z; wn[4 * q + 3] = d.w;
        }
    }

    // input-side constants (I == 1, so gi[g] = x_t * w_ih[g] + b_ih[g])
    const float wih_r = w_ih[j];
    const float wih_z = w_ih[j + kH];
    const float wih_n = w_ih[j + 2 * kH];
    // r/z gates: b_ih + b_hh always appear summed -> fold
    const float bias_r = b_ih[j] + b_hh[j];
    const float bias_z = b_ih[j + kH] + b_hh[j + kH];
    // n gate: b_hh_n is scaled by r, keep separate
    const float bi_n = b_ih[j + 2 * kH];
    const float bh_n = b_hh[j + 2 * kH];

    float h = 0.0f;
    hbuf[g][j] = 0.0f;  // same-wave write precedes all reads (lockstep)

    const float4* xrow4 = reinterpret_cast<const float4*>(x + (size_t)b * kT);
    const float4* hb4   = reinterpret_cast<const float4*>(&hbuf[g][0]);

    float4 xv = xrow4[0];  // prefetched x for the upcoming 4 timesteps

    for (int t0 = 0; t0 < kT; t0 += 4) {
        // prefetch next 4 inputs ~1000 cycles ahead of use
        const int nq = (t0 + 4 < kT) ? (t0 >> 2) + 1 : (t0 >> 2);
        float4 xnext = xrow4[nq];

#pragma unroll
        for (int tt = 0; tt < 4; ++tt) {
            const float xt = (tt == 0) ? xv.x : (tt == 1) ? xv.y
                           : (tt == 2) ? xv.z : xv.w;

            float ar = fmaf(xt, wih_r, bias_r);   // r pre-activation
            float az = fmaf(xt, wih_z, bias_z);   // z pre-activation
            float an = bh_n;                      // h-side of n gate

            // gh = w_hh[row] . h  (h broadcast from LDS, weights in VGPRs)
#pragma unroll
            for (int q = 0; q < kH / 4; ++q) {
                float4 hk = hb4[q];
                ar = fmaf(wr[4 * q + 0], hk.x, ar);
                ar = fmaf(wr[4 * q + 1], hk.y, ar);
                ar = fmaf(wr[4 * q + 2], hk.z, ar);
                ar = fmaf(wr[4 * q + 3], hk.w, ar);
                az = fmaf(wz[4 * q + 0], hk.x, az);
                az = fmaf(wz[4 * q + 1], hk.y, az);
                az = fmaf(wz[4 * q + 2], hk.z, az);
                az = fmaf(wz[4 * q + 3], hk.w, az);
                an = fmaf(wn[4 * q + 0], hk.x, an);
                an = fmaf(wn[4 * q + 1], hk.y, an);
                an = fmaf(wn[4 * q + 2], hk.z, an);
                an = fmaf(wn[4 * q + 3], hk.w, an);
            }

            const float r  = fast_sigmoid(ar);
            const float z  = fast_sigmoid(az);
            const float in_n = fmaf(xt, wih_n, bi_n);
            const float n  = fast_tanh(fmaf(r, an, in_n));
            h = fmaf(z, h - n, n);   // (1-z)*n + z*h

            hbuf[g][j] = h;          // publish for next timestep (same wave)
        }
        xv = xnext;
    }

    // ---- FC epilogue: out[b][o] = fc_w[o] . h + fc_b[o], o < 12 ----
    if (j < kO) {
        float acc = fc_b[j];
        const float* fw = fc_w + j * kH;
#pragma unroll
        for (int k = 0; k < kH; ++k)
            acc = fmaf(fw[k], hbuf[g][k], acc);
        out[(size_t)b * kO + j] = acc;
    }
}

}  // namespace

extern "C" void kernel_launch(void* const* d_in, const int* in_sizes, int n_in,
                              void* d_out, int out_size, void* d_ws, size_t ws_size,
                              hipStream_t stream) {
    const float* x    = (const float*)d_in[0];
    const float* w_ih = (const float*)d_in[1];
    const float* w_hh = (const float*)d_in[2];
    const float* b_ih = (const float*)d_in[3];
    const float* b_hh = (const float*)d_in[4];
    const float* fc_w = (const float*)d_in[5];
    const float* fc_b = (const float*)d_in[6];
    float* out = (float*)d_out;

    const int B = 4096;
    dim3 grid(B / kGroups);   // 512 blocks
    dim3 block(256);          // 8 batch elements per block
    gru_fused<<<grid, block, 0, stream>>>(x, w_ih, w_hh, b_ih, b_hh, fc_w, fc_b, out);
}

// Round 3
// 170.858 us; speedup vs baseline: 1.1923x; 1.1923x over previous
//
#include <hip/hip_runtime.h>

// GRU (B=4096, T=512, I=1, H=32) + FC(32->12), fused, dot2-f16 matvec.
//
// Layout: lane = (batch, hidden unit j). 32 lanes per batch element,
// 2 per wave64, 8 per 256-thread block -> 2048 waves = 2 waves/SIMD.
// State h stays f32 per-lane; an f16 copy is published through LDS each
// timestep and consumed as packed f16x2 pairs by v_dot2_f32_f16
// (2 MACs/instr, f32 accumulate): 96 fma -> 48 dot2 per timestep, and the
// per-lane weight file shrinks 96 -> 48 VGPRs (fixes the round-1 register
// demotion seen as VGPR_Count=68 + 2.3x VALU bloat).
// exp scale folding: sigmoid gates' weights pre-scaled by -log2(e), n-gate
// by +2*log2(e), so activations use raw v_exp_f32 (2^x) with no preamble.

namespace {

typedef _Float16 f16x2 __attribute__((ext_vector_type(2)));
typedef _Float16 f16x8 __attribute__((ext_vector_type(8)));

constexpr int kH = 32;
constexpr int kT = 512;
constexpr int kO = 12;
constexpr int kG = 8;  // batch elements (groups) per 256-thread block

__device__ __forceinline__ float fast_exp2(float a) {
#if __has_builtin(__builtin_amdgcn_exp2f)
    return __builtin_amdgcn_exp2f(a);
#else
    return exp2f(a);
#endif
}
__device__ __forceinline__ float fast_rcp(float a) {
#if __has_builtin(__builtin_amdgcn_rcpf)
    return __builtin_amdgcn_rcpf(a);
#else
    return 1.0f / a;
#endif
}

__device__ __forceinline__ float dot2(f16x2 a, f16x2 b, float c) {
#if __has_builtin(__builtin_amdgcn_fdot2)
    return __builtin_amdgcn_fdot2(a, b, c, false);
#else
    return fmaf((float)a[1], (float)b[1], fmaf((float)a[0], (float)b[0], c));
#endif
}

union V8 {
    f16x8 v;
    f16x2 p[4];
};

__global__ __launch_bounds__(256, 2) void gru_fused(
    const float* __restrict__ x,      // [4096, 512, 1]
    const float* __restrict__ w_ih,   // [96, 1]
    const float* __restrict__ w_hh,   // [96, 32]
    const float* __restrict__ b_ih,   // [96]
    const float* __restrict__ b_hh,   // [96]
    const float* __restrict__ fc_w,   // [12, 32]
    const float* __restrict__ fc_b,   // [12]
    float* __restrict__ out)          // [4096, 12]
{
    __shared__ _Float16 hbuf[kG][kH];   // f16 h for the matvec
    __shared__ float    hfin[kG][kH];   // f32 final h for the FC epilogue

    const int tid = threadIdx.x;
    const int g   = tid >> 5;           // batch slot within block
    const int j   = tid & 31;           // hidden unit owned by this lane
    const int b   = blockIdx.x * kG + g;

    const float kL2E = 1.4426950408889634f;   // log2(e)

    // ---- per-lane weights: rows j (r), j+32 (z), j+64 (n), f16x2-packed,
    //      exp-scale folded: r,z by -log2e ; n by +2*log2e ----
    f16x2 wr[kH / 2], wz[kH / 2], wn[kH / 2];
    {
        const float* Wr = w_hh + (size_t)j * kH;
        const float* Wz = w_hh + (size_t)(j + kH) * kH;
        const float* Wn = w_hh + (size_t)(j + 2 * kH) * kH;
#pragma unroll
        for (int m = 0; m < kH / 2; ++m) {
            wr[m] = f16x2{(_Float16)(-kL2E * Wr[2 * m]),
                          (_Float16)(-kL2E * Wr[2 * m + 1])};
            wz[m] = f16x2{(_Float16)(-kL2E * Wz[2 * m]),
                          (_Float16)(-kL2E * Wz[2 * m + 1])};
            wn[m] = f16x2{(_Float16)(2.0f * kL2E * Wn[2 * m]),
                          (_Float16)(2.0f * kL2E * Wn[2 * m + 1])};
        }
    }

    // input-side constants (I == 1), same scale folding
    const float wih_r = -kL2E * w_ih[j];
    const float wih_z = -kL2E * w_ih[j + kH];
    const float wih_n = 2.0f * kL2E * w_ih[j + 2 * kH];
    const float bias_r = -kL2E * (b_ih[j] + b_hh[j]);
    const float bias_z = -kL2E * (b_ih[j + kH] + b_hh[j + kH]);
    const float bi_n = 2.0f * kL2E * b_ih[j + 2 * kH];
    const float bh_n = 2.0f * kL2E * b_hh[j + 2 * kH];

    float h = 0.0f;
    hbuf[g][j] = (_Float16)0.0f;  // same-wave write precedes all reads

    const float4* xrow4 = reinterpret_cast<const float4*>(x + (size_t)b * kT);
    const f16x8*  hb8   = reinterpret_cast<const f16x8*>(&hbuf[g][0]);

    float4 xv = xrow4[0];

    for (int t0 = 0; t0 < kT; t0 += 4) {
        const int nq = (t0 + 4 < kT) ? (t0 >> 2) + 1 : (t0 >> 2);
        float4 xnext = xrow4[nq];

#pragma unroll
        for (int tt = 0; tt < 4; ++tt) {
            const float xt = (tt == 0) ? xv.x : (tt == 1) ? xv.y
                           : (tt == 2) ? xv.z : xv.w;

            float ar = fmaf(xt, wih_r, bias_r);   // -log2e * (r preact)
            float az = fmaf(xt, wih_z, bias_z);   // -log2e * (z preact)
            float an = bh_n;                      // +2log2e * (h-side n)
            const float inn = fmaf(xt, wih_n, bi_n);

            // h vector: 4x ds_read_b128 (broadcast within each 32-lane half)
            V8 u0, u1, u2, u3;
            u0.v = hb8[0]; u1.v = hb8[1]; u2.v = hb8[2]; u3.v = hb8[3];
            f16x2 hp[kH / 2];
#pragma unroll
            for (int p = 0; p < 4; ++p) {
                hp[0 + p]  = u0.p[p];
                hp[4 + p]  = u1.p[p];
                hp[8 + p]  = u2.p[p];
                hp[12 + p] = u3.p[p];
            }

#pragma unroll
            for (int m = 0; m < kH / 2; ++m) {
                ar = dot2(wr[m], hp[m], ar);
                az = dot2(wz[m], hp[m], az);
                an = dot2(wn[m], hp[m], an);
            }

            // sigmoid(a) = 1/(1+2^(-log2e*a)) ; ar,az already scaled
            const float r = fast_rcp(1.0f + fast_exp2(ar));
            const float z = fast_rcp(1.0f + fast_exp2(az));
            // tanh(y) = 1 - 2/(2^(2log2e*y)+1) ; inn,an already scaled
            const float targ = fmaf(r, an, inn);
            const float n = fmaf(-2.0f, fast_rcp(1.0f + fast_exp2(targ)), 1.0f);
            h = fmaf(z, h - n, n);                // (1-z)*n + z*h

            hbuf[g][j] = (_Float16)h;             // publish for next step
        }
        xv = xnext;
    }

    // ---- FC epilogue: out[b][o] = fc_w[o] . h + fc_b[o] ----
    hfin[g][j] = h;
    if (j < kO) {
        float acc = fc_b[j];
        const float* fw = fc_w + (size_t)j * kH;
#pragma unroll
        for (int k = 0; k < kH; ++k)
            acc = fmaf(fw[k], hfin[g][k], acc);
        out[(size_t)b * kO + j] = acc;
    }
}

}  // namespace

extern "C" void kernel_launch(void* const* d_in, const int* in_sizes, int n_in,
                              void* d_out, int out_size, void* d_ws, size_t ws_size,
                              hipStream_t stream) {
    const float* x    = (const float*)d_in[0];
    const float* w_ih = (const float*)d_in[1];
    const float* w_hh = (const float*)d_in[2];
    const float* b_ih = (const float*)d_in[3];
    const float* b_hh = (const float*)d_in[4];
    const float* fc_w = (const float*)d_in[5];
    const float* fc_b = (const float*)d_in[6];
    float* out = (float*)d_out;

    dim3 grid(4096 / kG);   // 512 blocks
    dim3 block(256);        // 8 batch elements per block
    gru_fused<<<grid, block, 0, stream>>>(x, w_ih, w_hh, b_ih, b_hh, fc_w, fc_b, out);
}

// Round 4
// 157.646 us; speedup vs baseline: 1.2922x; 1.0838x over previous
//
#include <hip/hip_runtime.h>

// GRU (B=4096, T=512, I=1, H=32) + FC(32->12), fused, dot2-f16 matvec.
//
// Layout: lane = (batch, hidden unit j). 32 lanes per batch element,
// 2 per wave64, 8 per 256-thread block -> 2048 waves = 2 waves/SIMD.
// State h stays f32 per-lane; an f16 copy is published through LDS each
// timestep and consumed as packed f16x2 pairs by v_dot2_f32_f16.
//
// amdgpu_waves_per_eu(2,2): the grid provides exactly 2 waves/SIMD, so pin
// the compiler's occupancy target to 2 (VGPR budget 256). Without the max,
// the scheduler targeted 8 waves/EU (<=64 VGPRs), demoted the 48-reg weight
// file to AGPRs, and paid ~1 v_accvgpr_read per dot2 (round-3: VGPR=48,
// 318 issue-cyc/timestep vs ~150 floor).
//
// exp scale folding: sigmoid gates' weights pre-scaled by -log2(e), n-gate
// by +2*log2(e), so activations use raw v_exp_f32 (2^x) with no preamble.

namespace {

typedef _Float16 f16x2 __attribute__((ext_vector_type(2)));
typedef _Float16 f16x8 __attribute__((ext_vector_type(8)));

constexpr int kH = 32;
constexpr int kT = 512;
constexpr int kO = 12;
constexpr int kG = 8;  // batch elements (groups) per 256-thread block

__device__ __forceinline__ float fast_exp2(float a) {
#if __has_builtin(__builtin_amdgcn_exp2f)
    return __builtin_amdgcn_exp2f(a);
#else
    return exp2f(a);
#endif
}
__device__ __forceinline__ float fast_rcp(float a) {
#if __has_builtin(__builtin_amdgcn_rcpf)
    return __builtin_amdgcn_rcpf(a);
#else
    return 1.0f / a;
#endif
}

__device__ __forceinline__ float dot2(f16x2 a, f16x2 b, float c) {
#if __has_builtin(__builtin_amdgcn_fdot2)
    return __builtin_amdgcn_fdot2(a, b, c, false);
#else
    return fmaf((float)a[1], (float)b[1], fmaf((float)a[0], (float)b[0], c));
#endif
}

union V8 {
    f16x8 v;
    f16x2 p[4];
};

__global__ __launch_bounds__(256)
__attribute__((amdgpu_waves_per_eu(2, 2)))
void gru_fused(
    const float* __restrict__ x,      // [4096, 512, 1]
    const float* __restrict__ w_ih,   // [96, 1]
    const float* __restrict__ w_hh,   // [96, 32]
    const float* __restrict__ b_ih,   // [96]
    const float* __restrict__ b_hh,   // [96]
    const float* __restrict__ fc_w,   // [12, 32]
    const float* __restrict__ fc_b,   // [12]
    float* __restrict__ out)          // [4096, 12]
{
    __shared__ _Float16 hbuf[kG][kH];   // f16 h for the matvec
    __shared__ float    hfin[kG][kH];   // f32 final h for the FC epilogue

    const int tid = threadIdx.x;
    const int g   = tid >> 5;           // batch slot within block
    const int j   = tid & 31;           // hidden unit owned by this lane
    const int b   = blockIdx.x * kG + g;

    const float kL2E = 1.4426950408889634f;   // log2(e)

    // ---- per-lane weights: rows j (r), j+32 (z), j+64 (n), f16x2-packed,
    //      exp-scale folded: r,z by -log2e ; n by +2*log2e ----
    f16x2 wr[kH / 2], wz[kH / 2], wn[kH / 2];
    {
        const float* Wr = w_hh + (size_t)j * kH;
        const float* Wz = w_hh + (size_t)(j + kH) * kH;
        const float* Wn = w_hh + (size_t)(j + 2 * kH) * kH;
#pragma unroll
        for (int m = 0; m < kH / 2; ++m) {
            wr[m] = f16x2{(_Float16)(-kL2E * Wr[2 * m]),
                          (_Float16)(-kL2E * Wr[2 * m + 1])};
            wz[m] = f16x2{(_Float16)(-kL2E * Wz[2 * m]),
                          (_Float16)(-kL2E * Wz[2 * m + 1])};
            wn[m] = f16x2{(_Float16)(2.0f * kL2E * Wn[2 * m]),
                          (_Float16)(2.0f * kL2E * Wn[2 * m + 1])};
        }
    }

    // input-side constants (I == 1), same scale folding
    const float wih_r = -kL2E * w_ih[j];
    const float wih_z = -kL2E * w_ih[j + kH];
    const float wih_n = 2.0f * kL2E * w_ih[j + 2 * kH];
    const float bias_r = -kL2E * (b_ih[j] + b_hh[j]);
    const float bias_z = -kL2E * (b_ih[j + kH] + b_hh[j + kH]);
    const float bi_n = 2.0f * kL2E * b_ih[j + 2 * kH];
    const float bh_n = 2.0f * kL2E * b_hh[j + 2 * kH];

    float h = 0.0f;
    hbuf[g][j] = (_Float16)0.0f;  // same-wave write precedes all reads

    const float4* xrow4 = reinterpret_cast<const float4*>(x + (size_t)b * kT);
    const f16x8*  hb8   = reinterpret_cast<const f16x8*>(&hbuf[g][0]);

    float4 xv = xrow4[0];

    for (int t0 = 0; t0 < kT; t0 += 4) {
        const int nq = (t0 + 4 < kT) ? (t0 >> 2) + 1 : (t0 >> 2);
        float4 xnext = xrow4[nq];

#pragma unroll
        for (int tt = 0; tt < 4; ++tt) {
            const float xt = (tt == 0) ? xv.x : (tt == 1) ? xv.y
                           : (tt == 2) ? xv.z : xv.w;

            float ar = fmaf(xt, wih_r, bias_r);   // -log2e * (r preact)
            float az = fmaf(xt, wih_z, bias_z);   // -log2e * (z preact)
            float an = bh_n;                      // +2log2e * (h-side n)
            const float inn = fmaf(xt, wih_n, bi_n);

            // h vector: 4x ds_read_b128 (broadcast within each 32-lane half)
            V8 u0, u1, u2, u3;
            u0.v = hb8[0]; u1.v = hb8[1]; u2.v = hb8[2]; u3.v = hb8[3];
            f16x2 hp[kH / 2];
#pragma unroll
            for (int p = 0; p < 4; ++p) {
                hp[0 + p]  = u0.p[p];
                hp[4 + p]  = u1.p[p];
                hp[8 + p]  = u2.p[p];
                hp[12 + p] = u3.p[p];
            }

#pragma unroll
            for (int m = 0; m < kH / 2; ++m) {
                ar = dot2(wr[m], hp[m], ar);
                az = dot2(wz[m], hp[m], az);
                an = dot2(wn[m], hp[m], an);
            }

            // sigmoid(a) = 1/(1+2^(-log2e*a)) ; ar,az already scaled
            const float r = fast_rcp(1.0f + fast_exp2(ar));
            const float z = fast_rcp(1.0f + fast_exp2(az));
            // tanh(y) = 1 - 2/(2^(2log2e*y)+1) ; inn,an already scaled
            const float targ = fmaf(r, an, inn);
            const float n = fmaf(-2.0f, fast_rcp(1.0f + fast_exp2(targ)), 1.0f);
            h = fmaf(z, h - n, n);                // (1-z)*n + z*h

            hbuf[g][j] = (_Float16)h;             // publish for next step
        }
        xv = xnext;
    }

    // ---- FC epilogue: out[b][o] = fc_w[o] . h + fc_b[o] ----
    hfin[g][j] = h;
    if (j < kO) {
        float acc = fc_b[j];
        const float* fw = fc_w + (size_t)j * kH;
#pragma unroll
        for (int k = 0; k < kH; ++k)
            acc = fmaf(fw[k], hfin[g][k], acc);
        out[(size_t)b * kO + j] = acc;
    }
}

}  // namespace

extern "C" void kernel_launch(void* const* d_in, const int* in_sizes, int n_in,
                              void* d_out, int out_size, void* d_ws, size_t ws_size,
                              hipStream_t stream) {
    const float* x    = (const float*)d_in[0];
    const float* w_ih = (const float*)d_in[1];
    const float* w_hh = (const float*)d_in[2];
    const float* b_ih = (const float*)d_in[3];
    const float* b_hh = (const float*)d_in[4];
    const float* fc_w = (const float*)d_in[5];
    const float* fc_b = (const float*)d_in[6];
    float* out = (float*)d_out;

    dim3 grid(4096 / kG);   // 512 blocks
    dim3 block(256);        // 8 batch elements per block
    gru_fused<<<grid, block, 0, stream>>>(x, w_ih, w_hh, b_ih, b_hh, fc_w, fc_b, out);
}